// Round 5
// baseline (173.397 us; speedup 1.0000x reference)
//
#include <hip/hip_runtime.h>
#include <math.h>

#define T_N 100000
#define H_N 256
#define NT16 (T_N / 16)        // 6250 16-row tiles, exact
#define NW 12                  // waves per k_at block
#define NB 256                 // k_at grid
#define TOTW (NW * NB)         // 3072 waves

typedef __attribute__((ext_vector_type(8))) __bf16 bf16x8;
typedef __attribute__((ext_vector_type(4))) float f32x4;

// ws layout (bytes):
//       0 : WmT bf16 [256][256]   (131072)
//  131072 : proj f32 [256]        (1024)
//  132096 : At   f32 [100000]     (400000)
//  532096 : part2 float2[3072]    (24576)
//  556672 : s1g  f32[256]         (1024)
//  557696 : s0g  f32[256]         (1024)
//  558720 : lse  f32              (4)

__device__ __forceinline__ float tanh_fast(float x) {
    // tanh(x) = 1 - 2/(exp(2x)+1); saturates correctly for large |x|
    float e = __expf(2.0f * x);
    return 1.0f - 2.0f / (e + 1.0f);
}

// ---------------------------------------------------------------- prep
__global__ __launch_bounds__(256) void k_prep(const float* __restrict__ Wm,
                                              const float* __restrict__ hc,
                                              const float* __restrict__ W1,
                                              __bf16* __restrict__ WmT,
                                              float* __restrict__ proj,
                                              float* __restrict__ s1g,
                                              float* __restrict__ s0g) {
    const int j = blockIdx.x;   // 0..255
    const int t = threadIdx.x;  // 0..255
    WmT[j * H_N + t] = (__bf16)Wm[t * H_N + j];   // B^T, k-contiguous
    __shared__ float red[H_N];
    red[t] = hc[t] * W1[j * H_N + t];
    __syncthreads();
    for (int off = 128; off > 0; off >>= 1) {
        if (t < off) red[t] += red[t + off];
        __syncthreads();
    }
    if (t == 0) proj[j] = red[0];
    if (j == 0) { s1g[t] = 0.0f; s0g[t] = 0.0f; }
}

// ---------------------------------------------------------------- fused At + LSE + ct partials
// B (256x256 bf16) in LDS, loaded once. Each wave independently processes
// 16-row tiles: A-fragments straight from global (fp32->bf16 in reg),
// 16x16x32 MFMA over all 256 cols, tanh/V epilogue, online LSE, ct partials
// from coalesced fp32 re-read (L3-hot). NO barriers in the main loop.
__global__ __launch_bounds__(768, 3) void k_at(const float* __restrict__ Mt,
                                               const __bf16* __restrict__ WmT,
                                               const float* __restrict__ proj,
                                               const float* __restrict__ V,
                                               float* __restrict__ At,
                                               float2* __restrict__ part2,
                                               float* __restrict__ s1g,
                                               float* __restrict__ s0g) {
    const int tid = threadIdx.x;
    const int lane = tid & 63;
    const int w = tid >> 6;      // 0..11
    const int l15 = lane & 15;
    const int lg = lane >> 4;    // 0..3

    struct SMem {
        __align__(16) char sB[131072];   // bf16 [n=256][k=256], XOR-swizzled
        float proj_l[256];
        float v_l[256];
        float wave_at[NW * 16];
    };
    __shared__ SMem sm;

    // ---- cooperative sB load (WmT is L2-resident, 128 KB), swizzled
    for (int idx = tid; idx < 8192; idx += 768) {
        const int n = idx >> 5;          // row (col of Wm)
        const int c = (idx & 31) << 4;   // byte within 512B row
        const bf16x8 v = *(const bf16x8*)(WmT + n * H_N + (c >> 1));
        *(bf16x8*)(&sm.sB[(n * 512 + c) ^ ((n & 7) << 4)]) = v;
    }
    if (tid < 256) { sm.proj_l[tid] = proj[tid]; sm.v_l[tid] = V[tid]; }
    __syncthreads();

    float s1a[4] = {0.f, 0.f, 0.f, 0.f};
    float s0a[4] = {0.f, 0.f, 0.f, 0.f};
    float lm = -1e30f, ls = 0.0f;

    for (int tau = blockIdx.x * NW + w; tau < NT16; tau += TOTW) {
        const int t0 = tau * 16;
        const float* arow = Mt + (size_t)(t0 + l15) * H_N;

        f32x4 acc[16];
#pragma unroll
        for (int fc = 0; fc < 16; ++fc) {
            f32x4 z = {0.f, 0.f, 0.f, 0.f};
            acc[fc] = z;
        }

#pragma unroll
        for (int ks = 0; ks < 8; ++ks) {
            const float4 a0 = *(const float4*)(arow + 32 * ks + 8 * lg);
            const float4 a1 = *(const float4*)(arow + 32 * ks + 8 * lg + 4);
            bf16x8 af;
            af[0] = (__bf16)a0.x; af[1] = (__bf16)a0.y;
            af[2] = (__bf16)a0.z; af[3] = (__bf16)a0.w;
            af[4] = (__bf16)a1.x; af[5] = (__bf16)a1.y;
            af[6] = (__bf16)a1.z; af[7] = (__bf16)a1.w;
#pragma unroll
            for (int fc = 0; fc < 16; ++fc) {
                const int n = 16 * fc + l15;
                const bf16x8 bf = *(const bf16x8*)(
                    &sm.sB[(n * 512 + 64 * ks + 16 * lg) ^ ((n & 7) << 4)]);
                acc[fc] = __builtin_amdgcn_mfma_f32_16x16x32_bf16(af, bf, acc[fc], 0, 0, 0);
            }
        }

        // ---- epilogue: per row (4lg+i), sum over 256 cols of tanh(y+proj)*V
#pragma unroll
        for (int i = 0; i < 4; ++i) {
            float p = 0.f;
#pragma unroll
            for (int fc = 0; fc < 16; ++fc) {
                const int n = 16 * fc + l15;
                p += tanh_fast(acc[fc][i] + sm.proj_l[n]) * sm.v_l[n];
            }
            p += __shfl_xor(p, 1);
            p += __shfl_xor(p, 2);
            p += __shfl_xor(p, 4);
            p += __shfl_xor(p, 8);
            if (l15 == 0) {
                const int r = 4 * lg + i;
                At[t0 + r] = p;
                sm.wave_at[w * 16 + r] = p;
                // online LSE (only these 4 lanes carry real data)
                if (p > lm) { ls = ls * __expf(lm - p) + 1.0f; lm = p; }
                else ls += __expf(p - lm);
            }
        }

        // ---- ct partials: re-read the fp32 tile (coalesced, L3-hot)
        const int c0 = 4 * lane;
#pragma unroll
        for (int r = 0; r < 16; ++r) {
            const float atr = sm.wave_at[w * 16 + r];  // broadcast
            const float4 mv = *(const float4*)(Mt + (size_t)(t0 + r) * H_N + c0);
            s1a[0] += atr * mv.x; s0a[0] += mv.x;
            s1a[1] += atr * mv.y; s0a[1] += mv.y;
            s1a[2] += atr * mv.z; s0a[2] += mv.z;
            s1a[3] += atr * mv.w; s0a[3] += mv.w;
        }
    }

    // ---- block reduce of ct partials (reuse sB area), then global atomics
    __syncthreads();
    float* red = (float*)sm.sB;  // [2][12][256] floats = 24 KB
    {
        const int c0 = 4 * lane;
#pragma unroll
        for (int q = 0; q < 4; ++q) {
            red[w * 256 + c0 + q] = s1a[q];
            red[3072 + w * 256 + c0 + q] = s0a[q];
        }
    }
    __syncthreads();
    if (tid < 256) {
        float a = 0.f;
#pragma unroll
        for (int g = 0; g < NW; ++g) a += red[g * 256 + tid];
        atomicAdd(&s1g[tid], a);
    } else if (tid < 512) {
        const int c = tid - 256;
        float a = 0.f;
#pragma unroll
        for (int g = 0; g < NW; ++g) a += red[3072 + g * 256 + c];
        atomicAdd(&s0g[c], a);
    }

    // ---- per-wave LSE partial -> part2[wave]
    {
#pragma unroll
        for (int d = 1; d < 64; d <<= 1) {
            const float m2 = __shfl_xor(lm, d), s2 = __shfl_xor(ls, d);
            const float M = fmaxf(lm, m2);
            ls = ls * __expf(lm - M) + s2 * __expf(m2 - M);
            lm = M;
        }
        if (lane == 0) part2[blockIdx.x * NW + w] = make_float2(lm, ls);
    }
}

// ---------------------------------------------------------------- final: LSE + ct
__global__ __launch_bounds__(1024) void k_final(const float2* __restrict__ part2,
                                                const float* __restrict__ s1g,
                                                const float* __restrict__ s0g,
                                                float* __restrict__ lse,
                                                float* __restrict__ out) {
    const int tid = threadIdx.x;
    float lm = -1e30f, ls = 0.0f;
    for (int i = tid; i < TOTW; i += 1024) {
        const float2 p = part2[i];
        const float M = fmaxf(lm, p.x);
        ls = ls * __expf(lm - M) + p.y * __expf(p.x - M);
        lm = M;
    }
    __shared__ float ms[1024], ss[1024];
    ms[tid] = lm; ss[tid] = ls;
    __syncthreads();
    for (int off = 512; off > 0; off >>= 1) {
        if (tid < off) {
            const float m2 = ms[tid + off], s2 = ss[tid + off];
            const float M = fmaxf(ms[tid], m2);
            ss[tid] = ss[tid] * __expf(ms[tid] - M) + s2 * __expf(m2 - M);
            ms[tid] = M;
        }
        __syncthreads();
    }
    __shared__ float Ls;
    if (tid == 0) { Ls = ms[0] + logf(ss[0]); *lse = Ls; }
    __syncthreads();
    if (tid < H_N) out[T_N + tid] = s1g[tid] - Ls * s0g[tid];
}

// ---------------------------------------------------------------- alphat = At - LSE
__global__ __launch_bounds__(256) void k_alpha(const float* __restrict__ At,
                                               const float* __restrict__ lse,
                                               float* __restrict__ out) {
    const float L = *lse;
    const int i4 = blockIdx.x * 256 + threadIdx.x;
    if (i4 < T_N / 4) {
        float4 a = *(const float4*)(At + i4 * 4);
        a.x -= L; a.y -= L; a.z -= L; a.w -= L;
        *(float4*)(out + i4 * 4) = a;
    }
}

// ----------------------------------------------------------------
extern "C" void kernel_launch(void* const* d_in, const int* in_sizes, int n_in,
                              void* d_out, int out_size, void* d_ws, size_t ws_size,
                              hipStream_t stream) {
    const float* inputs = (const float*)d_in[0];  // (T, H)
    const float* hc     = (const float*)d_in[1];  // (1, H)
    const float* Wm     = (const float*)d_in[2];  // (H, H)
    const float* V      = (const float*)d_in[3];  // (H, 1)
    const float* W1     = (const float*)d_in[4];  // (H, H)
    float* out = (float*)d_out;                   // [alphat (T) | ct (H)]

    char* ws = (char*)d_ws;
    __bf16* WmT  = (__bf16*)ws;
    float* proj  = (float*)(ws + 131072);
    float* At    = (float*)(ws + 132096);
    float2* p2   = (float2*)(ws + 532096);
    float* s1g   = (float*)(ws + 556672);
    float* s0g   = (float*)(ws + 557696);
    float* lse   = (float*)(ws + 558720);

    k_prep<<<256, 256, 0, stream>>>(Wm, hc, W1, WmT, proj, s1g, s0g);
    k_at<<<NB, NW * 64, 0, stream>>>(inputs, WmT, proj, V, At, p2, s1g, s0g);
    k_final<<<1, 1024, 0, stream>>>(p2, s1g, s0g, lse, out);
    k_alpha<<<98, 256, 0, stream>>>(At, lse, out);
}

// Round 6
// 94.054 us; speedup vs baseline: 1.8436x; 1.8436x over previous
//
#include <hip/hip_runtime.h>
#include <math.h>

#define T_N 100000
#define H_N 256
#define TM 48                       // rows per tile
#define NTILE ((T_N + TM - 1) / TM) // 2084 (last tile 16 real rows)
#define NB 256                      // persistent blocks, 1/CU

typedef __attribute__((ext_vector_type(8))) __bf16 bf16x8;
typedef __attribute__((ext_vector_type(4))) __bf16 bf16x4;
typedef __attribute__((ext_vector_type(4))) float f32x4;

// ws layout (bytes):
//       0 : WmT bf16 [256][256]   (131072)
//  131072 : proj f32 [256]        (1024)
//  132096 : At   f32 [100000]     (400000)
//  532096 : part2 float2[256]     (2048)
//  536192 : s1g  f32[256]         (1024)
//  537216 : s0g  f32[256]         (1024)
//  538240 : lse  f32              (4)

__device__ __forceinline__ float tanh_fast(float x) {
    float e = __expf(2.0f * x);
    return 1.0f - 2.0f / (e + 1.0f);
}

// ---------------------------------------------------------------- prep
__global__ __launch_bounds__(256) void k_prep(const float* __restrict__ Wm,
                                              const float* __restrict__ hc,
                                              const float* __restrict__ W1,
                                              __bf16* __restrict__ WmT,
                                              float* __restrict__ proj,
                                              float* __restrict__ s1g,
                                              float* __restrict__ s0g) {
    const int j = blockIdx.x;
    const int t = threadIdx.x;
    WmT[j * H_N + t] = (__bf16)Wm[t * H_N + j];   // B^T, k-contiguous
    __shared__ float red[H_N];
    red[t] = hc[t] * W1[j * H_N + t];
    __syncthreads();
    for (int off = 128; off > 0; off >>= 1) {
        if (t < off) red[t] += red[t + off];
        __syncthreads();
    }
    if (t == 0) proj[j] = red[0];
    if (j == 0) { s1g[t] = 0.0f; s0g[t] = 0.0f; }
}

// ---------------------------------------------------------------- fused At + LSE + ct partials
// 4 waves (256 thr), 1 block/CU. B: full 256x256 bf16 in LDS (swizzled), loaded
// once. A: 48-row tile (2 K-halves of 128) in LDS bf16; global loads issued one
// full tile ahead into regs, ds-written after the epilogue (T14 split).
// Wave w owns cols [64w, 64w+64): M_rep=3, N_rep=4, acc = 48 VGPR.
__global__ __launch_bounds__(256, 1) void k_at(const float* __restrict__ Mt,
                                               const __bf16* __restrict__ WmT,
                                               const float* __restrict__ proj,
                                               const float* __restrict__ V,
                                               float* __restrict__ At,
                                               float2* __restrict__ part2,
                                               float* __restrict__ s1g,
                                               float* __restrict__ s0g) {
    const int tid = threadIdx.x;
    const int lane = tid & 63;
    const int w = tid >> 6;
    const int l15 = lane & 15;
    const int lg = lane >> 4;

    struct SMem {
        __align__(16) char sB[131072];       // [n=256][k=256] bf16, XOR-swizzled
        __align__(16) char sA[2][TM * 256];  // per K-half: [48][128] bf16, swizzled
        float part[4][TM];
        float at_final[TM];
    };
    __shared__ SMem sm;

    // ---- B prologue: 128 KB from WmT (L2-hot after k_prep)
#pragma unroll
    for (int i = 0; i < 32; ++i) {
        const int g = tid + 256 * i;
        const int n = g >> 5;
        const int c8 = (g & 31) * 8;
        const bf16x8 v = *(const bf16x8*)(WmT + n * H_N + c8);
        *(bf16x8*)(&sm.sB[(n * 512 + c8 * 2) ^ ((n & 7) << 4)]) = v;
    }
    float pj[4], vj[4];
#pragma unroll
    for (int fc = 0; fc < 4; ++fc) {
        const int n = 64 * w + 16 * fc + l15;
        pj[fc] = proj[n];
        vj[fc] = V[n];
    }

    // staging: per K-half, 1536 float4; thread covers f = tid + 256i (i<6):
    // row = f>>5, kq = f&31 (float4 within the 128-float half)
    float4 R[2][6];
    auto gload = [&](int tile) {
#pragma unroll
        for (int h = 0; h < 2; ++h)
#pragma unroll
            for (int i = 0; i < 6; ++i) {
                const int f = tid + 256 * i;
                const int row = f >> 5;
                const int kq = f & 31;
                const int t = tile * TM + row;
                R[h][i] = (t < T_N)
                    ? *(const float4*)(Mt + (size_t)t * H_N + 128 * h + 4 * kq)
                    : make_float4(0.f, 0.f, 0.f, 0.f);
            }
    };
    auto dswrite = [&]() {
#pragma unroll
        for (int h = 0; h < 2; ++h)
#pragma unroll
            for (int i = 0; i < 6; ++i) {
                const int f = tid + 256 * i;
                const int row = f >> 5;
                const int kq = f & 31;
                bf16x4 b;
                b[0] = (__bf16)R[h][i].x; b[1] = (__bf16)R[h][i].y;
                b[2] = (__bf16)R[h][i].z; b[3] = (__bf16)R[h][i].w;
                *(bf16x4*)(&sm.sA[h][(row * 256 + 8 * kq) ^ ((row & 7) << 4)]) = b;
            }
    };

    float s1a[8] = {0.f,0.f,0.f,0.f,0.f,0.f,0.f,0.f};
    float s0a[8] = {0.f,0.f,0.f,0.f,0.f,0.f,0.f,0.f};
    float lm = -1e30f, ls = 0.0f;
    const int c0 = (tid & 31) * 8;   // ct cols c0..c0+8
    const int rb = tid >> 5;         // ct rows rb + 8i
    const int ch = c0 >> 7;          // which K-half holds these cols
    const int cl = c0 & 127;

    int tile = blockIdx.x;
    gload(tile);
    dswrite();
    gload(tile + NB);   // prefetch: ds-written at end of this tile's work
    __syncthreads();

    for (; tile < NTILE; tile += NB) {
        f32x4 acc[3][4];
#pragma unroll
        for (int m = 0; m < 3; ++m)
#pragma unroll
            for (int fc = 0; fc < 4; ++fc) {
                f32x4 z = {0.f, 0.f, 0.f, 0.f};
                acc[m][fc] = z;
            }

#pragma unroll
        for (int h = 0; h < 2; ++h)
#pragma unroll
            for (int ksg = 0; ksg < 4; ++ksg) {
                bf16x8 af[3], bf[4];
#pragma unroll
                for (int m = 0; m < 3; ++m) {
                    const int r = 16 * m + l15;
                    af[m] = *(const bf16x8*)(
                        &sm.sA[h][(r * 256 + 64 * ksg + 16 * lg) ^ ((r & 7) << 4)]);
                }
#pragma unroll
                for (int fc = 0; fc < 4; ++fc) {
                    const int n = 64 * w + 16 * fc + l15;
                    bf[fc] = *(const bf16x8*)(
                        &sm.sB[(n * 512 + 256 * h + 64 * ksg + 16 * lg) ^ ((n & 7) << 4)]);
                }
#pragma unroll
                for (int m = 0; m < 3; ++m)
#pragma unroll
                    for (int fc = 0; fc < 4; ++fc)
                        acc[m][fc] = __builtin_amdgcn_mfma_f32_16x16x32_bf16(
                            af[m], bf[fc], acc[m][fc], 0, 0, 0);
            }

        // ---- epilogue: row partials over this wave's 64 cols
#pragma unroll
        for (int m = 0; m < 3; ++m)
#pragma unroll
            for (int i = 0; i < 4; ++i) {
                float p = 0.f;
#pragma unroll
                for (int fc = 0; fc < 4; ++fc)
                    p += tanh_fast(acc[m][fc][i] + pj[fc]) * vj[fc];
                p += __shfl_xor(p, 1);
                p += __shfl_xor(p, 2);
                p += __shfl_xor(p, 4);
                p += __shfl_xor(p, 8);
                if (l15 == 0) sm.part[w][16 * m + 4 * lg + i] = p;
            }
        __syncthreads();  // part[] ready

        if (tid < TM) {
            const float at = sm.part[0][tid] + sm.part[1][tid]
                           + sm.part[2][tid] + sm.part[3][tid];
            const int t = tile * TM + tid;
            float atv = 0.f;
            if (t < T_N) {
                At[t] = at;
                atv = at;
                if (at > lm) { ls = ls * __expf(lm - at) + 1.0f; lm = at; }
                else ls += __expf(at - lm);
            }
            sm.at_final[tid] = atv;
        }
        __syncthreads();  // at_final ready

        // ---- ct partials from the bf16 tile in LDS
#pragma unroll
        for (int i = 0; i < 6; ++i) {
            const int row = rb + 8 * i;
            const float ar = sm.at_final[row];
            const bf16x8 x8 = *(const bf16x8*)(
                &sm.sA[ch][(row * 256 + 2 * cl) ^ ((row & 7) << 4)]);
#pragma unroll
            for (int q = 0; q < 8; ++q) {
                const float x = (float)x8[q];
                s1a[q] += ar * x;
                s0a[q] += x;
            }
        }
        __syncthreads();  // sA reads done

        dswrite();              // next tile into sA (R loaded a full tile ago)
        gload(tile + 2 * NB);   // issue loads for tile after next
        __syncthreads();        // sA ready for next iteration
    }

    // ---- block reduce of ct partials (reuse sB region)
    float* red1 = (float*)&sm.sB[0];      // [8][256]
    float* red2 = (float*)&sm.sB[8192];   // [8][256]
#pragma unroll
    for (int q = 0; q < 8; ++q) {
        red1[rb * 256 + c0 + q] = s1a[q];
        red2[rb * 256 + c0 + q] = s0a[q];
    }
    __syncthreads();
    {
        float a1 = 0.f, a0 = 0.f;
#pragma unroll
        for (int g = 0; g < 8; ++g) {
            a1 += red1[g * 256 + tid];
            a0 += red2[g * 256 + tid];
        }
        atomicAdd(&s1g[tid], a1);
        atomicAdd(&s0g[tid], a0);
    }

    // ---- block LSE partial: lm/ls live in wave-0 lanes (tid<48); reduce wave 0
    if (w == 0) {
#pragma unroll
        for (int d = 1; d < 64; d <<= 1) {
            const float m2 = __shfl_xor(lm, d), s2 = __shfl_xor(ls, d);
            const float M = fmaxf(lm, m2);
            ls = ls * __expf(lm - M) + s2 * __expf(m2 - M);
            lm = M;
        }
        if (lane == 0) part2[blockIdx.x] = make_float2(lm, ls);
    }
}

// ---------------------------------------------------------------- final: LSE + ct
__global__ __launch_bounds__(256) void k_final(const float2* __restrict__ part2,
                                               const float* __restrict__ s1g,
                                               const float* __restrict__ s0g,
                                               float* __restrict__ lse,
                                               float* __restrict__ out) {
    const int tid = threadIdx.x;
    __shared__ float ms[256], ss[256];
    const float2 p = part2[tid];
    ms[tid] = p.x; ss[tid] = p.y;
    __syncthreads();
    for (int off = 128; off > 0; off >>= 1) {
        if (tid < off) {
            const float m2 = ms[tid + off], s2 = ss[tid + off];
            const float M = fmaxf(ms[tid], m2);
            ss[tid] = ss[tid] * __expf(ms[tid] - M) + s2 * __expf(m2 - M);
            ms[tid] = M;
        }
        __syncthreads();
    }
    __shared__ float Ls;
    if (tid == 0) { Ls = ms[0] + logf(ss[0]); *lse = Ls; }
    __syncthreads();
    out[T_N + tid] = s1g[tid] - Ls * s0g[tid];
}

// ---------------------------------------------------------------- alphat = At - LSE
__global__ __launch_bounds__(256) void k_alpha(const float* __restrict__ At,
                                               const float* __restrict__ lse,
                                               float* __restrict__ out) {
    const float L = *lse;
    const int i4 = blockIdx.x * 256 + threadIdx.x;
    if (i4 < T_N / 4) {
        float4 a = *(const float4*)(At + i4 * 4);
        a.x -= L; a.y -= L; a.z -= L; a.w -= L;
        *(float4*)(out + i4 * 4) = a;
    }
}

// ----------------------------------------------------------------
extern "C" void kernel_launch(void* const* d_in, const int* in_sizes, int n_in,
                              void* d_out, int out_size, void* d_ws, size_t ws_size,
                              hipStream_t stream) {
    const float* inputs = (const float*)d_in[0];  // (T, H)
    const float* hc     = (const float*)d_in[1];  // (1, H)
    const float* Wm     = (const float*)d_in[2];  // (H, H)
    const float* V      = (const float*)d_in[3];  // (H, 1)
    const float* W1     = (const float*)d_in[4];  // (H, H)
    float* out = (float*)d_out;                   // [alphat (T) | ct (H)]

    char* ws = (char*)d_ws;
    __bf16* WmT  = (__bf16*)ws;
    float* proj  = (float*)(ws + 131072);
    float* At    = (float*)(ws + 132096);
    float2* p2   = (float2*)(ws + 532096);
    float* s1g   = (float*)(ws + 536192);
    float* s0g   = (float*)(ws + 537216);
    float* lse   = (float*)(ws + 538240);

    k_prep<<<256, 256, 0, stream>>>(Wm, hc, W1, WmT, proj, s1g, s0g);
    k_at<<<NB, 256, 0, stream>>>(inputs, WmT, proj, V, At, p2, s1g, s0g);
    k_final<<<1, 256, 0, stream>>>(p2, s1g, s0g, lse, out);
    k_alpha<<<98, 256, 0, stream>>>(At, lse, out);
}

// Round 7
// 87.791 us; speedup vs baseline: 1.9751x; 1.0713x over previous
//
#include <hip/hip_runtime.h>
#include <math.h>

#define T_N 100000
#define H_N 256
#define TM 32                  // tile rows
#define NT32 (T_N / TM)        // 3125 exact, no tail
#define NB_AT 256              // k_at grid (1 block/CU)

typedef __attribute__((ext_vector_type(8))) __bf16 bf16x8;
typedef __attribute__((ext_vector_type(4))) __bf16 bf16x4;
typedef __attribute__((ext_vector_type(4))) float f32x4;

// ws layout (bytes):
//       0 : WmT bf16 [256][256]   (131072)
//  131072 : proj f32 [256]        (1024)
//  132096 : At   f32 [100000]     (400000)
//  532096 : part2 float2[256]     (2048)
//  536192 : s1g  f32[256]         (1024)
//  537216 : s0g  f32[256]         (1024)
//  538240 : lse  f32              (4)

__device__ __forceinline__ float tanh_fast(float x) {
    float e = __expf(2.0f * x);
    return 1.0f - 2.0f / (e + 1.0f);
}

// ---------------------------------------------------------------- prep
__global__ __launch_bounds__(256) void k_prep(const float* __restrict__ Wm,
                                              const float* __restrict__ hc,
                                              const float* __restrict__ W1,
                                              __bf16* __restrict__ WmT,
                                              float* __restrict__ proj,
                                              float* __restrict__ s1g,
                                              float* __restrict__ s0g) {
    const int j = blockIdx.x;
    const int t = threadIdx.x;
    WmT[j * H_N + t] = (__bf16)Wm[t * H_N + j];   // B^T, k-contiguous
    __shared__ float red[H_N];
    red[t] = hc[t] * W1[j * H_N + t];
    __syncthreads();
    for (int off = 128; off > 0; off >>= 1) {
        if (t < off) red[t] += red[t + off];
        __syncthreads();
    }
    if (t == 0) proj[j] = red[0];
    if (j == 0) { s1g[t] = 0.0f; s0g[t] = 0.0f; }
}

// ---------------------------------------------------------------- fused At + ct partials
// 1024 thr = 16 waves (4/SIMD). Wave (wr=w>>3, wc=w&7): rows 16wr..+16,
// cols 32wc..+32 (acc[2] = 8 VGPR). B full in LDS; A 32-row tile staged via
// reg (T14 split), loads in flight across RAW barriers (no vmcnt drain).
// ct: each wave accumulates its own col-partial p_r * Mt-row; wave-sum = exact.
__global__ __launch_bounds__(1024, 4) void k_at(const float* __restrict__ Mt,
                                                const __bf16* __restrict__ WmT,
                                                const float* __restrict__ proj,
                                                const float* __restrict__ V,
                                                float* __restrict__ At,
                                                float* __restrict__ s1g,
                                                float* __restrict__ s0g) {
    const int tid = threadIdx.x;
    const int lane = tid & 63;
    const int w = tid >> 6;     // 0..15
    const int wr = w >> 3;      // 0..1
    const int wc = w & 7;       // 0..7
    const int l15 = lane & 15;
    const int lg = lane >> 4;

    struct SMem {
        __align__(16) char sB[131072];   // [n=256][k=256] bf16, XOR-swizzled
        __align__(16) char sA[TM * 512]; // [32][256] bf16, XOR-swizzled
        float part[16][16];              // [wave][row-in-group] col-partials
    };
    __shared__ SMem sm;

    // ---- stage B once (WmT L2-hot after k_prep)
#pragma unroll
    for (int i = 0; i < 8; ++i) {
        const int g = tid + 1024 * i;
        const int n = g >> 5;
        const int c8 = (g & 31) * 8;
        const bf16x8 v = *(const bf16x8*)(WmT + n * H_N + c8);
        *(bf16x8*)(&sm.sB[(n * 512 + c8 * 2) ^ ((n & 7) << 4)]) = v;
    }
    float pj[2], vj[2];
#pragma unroll
    for (int fc = 0; fc < 2; ++fc) {
        const int n = 32 * wc + 16 * fc + l15;
        pj[fc] = proj[n];
        vj[fc] = V[n];
    }

    // staging: 2048 float4-slots; f = i*1024+tid -> row=f>>6, c4=f&63
    float4 R[2];
    auto gload = [&](int tile) {
        const int tt = (tile < NT32) ? tile : (NT32 - 1);
#pragma unroll
        for (int i = 0; i < 2; ++i) {
            const int f = i * 1024 + tid;
            R[i] = *(const float4*)(Mt + (size_t)(tt * TM + (f >> 6)) * H_N + (f & 63) * 4);
        }
    };
    auto dswrite = [&]() {
#pragma unroll
        for (int i = 0; i < 2; ++i) {
            const int f = i * 1024 + tid;
            const int row = f >> 6, c4 = f & 63;
            bf16x4 b;
            b[0] = (__bf16)R[i].x; b[1] = (__bf16)R[i].y;
            b[2] = (__bf16)R[i].z; b[3] = (__bf16)R[i].w;
            *(bf16x4*)(&sm.sA[(row * 512 + c4 * 8) ^ ((row & 7) << 4)]) = b;
        }
    };

    float s1a[4] = {0.f, 0.f, 0.f, 0.f};
    float s0a[4] = {0.f, 0.f, 0.f, 0.f};
    const int c0 = lane * 4;   // ct cols c0..c0+3 (per wave: full 256)

    int tile = blockIdx.x;
    gload(tile);
    dswrite();                 // compiler vm-waits via reg dep
    __syncthreads();           // one-time full barrier (sB + sA visible)
    gload(tile + NB_AT);       // in flight across the whole first tile

    for (; tile < NT32; tile += NB_AT) {
        f32x4 acc[2];
#pragma unroll
        for (int fc = 0; fc < 2; ++fc) {
            f32x4 z = {0.f, 0.f, 0.f, 0.f};
            acc[fc] = z;
        }
        const int r = 16 * wr + l15;
#pragma unroll
        for (int ks = 0; ks < 8; ++ks) {
            const int kb = (32 * ks + 8 * lg) * 2;
            const bf16x8 af = *(const bf16x8*)(&sm.sA[(r * 512 + kb) ^ ((r & 7) << 4)]);
#pragma unroll
            for (int fc = 0; fc < 2; ++fc) {
                const int n = 32 * wc + 16 * fc + l15;
                const bf16x8 bf = *(const bf16x8*)(&sm.sB[(n * 512 + kb) ^ ((n & 7) << 4)]);
                acc[fc] = __builtin_amdgcn_mfma_f32_16x16x32_bf16(af, bf, acc[fc], 0, 0, 0);
            }
        }

        // ---- epilogue: col-partial row sums over this wave's 32 cols
#pragma unroll
        for (int i = 0; i < 4; ++i) {
            float p = tanh_fast(acc[0][i] + pj[0]) * vj[0]
                    + tanh_fast(acc[1][i] + pj[1]) * vj[1];
            p += __shfl_xor(p, 1);
            p += __shfl_xor(p, 2);
            p += __shfl_xor(p, 4);
            p += __shfl_xor(p, 8);
            if (l15 == 0) sm.part[w][4 * lg + i] = p;
        }

        // ---- ct partials with OWN wave's col-partial (sum over waves = exact)
#pragma unroll
        for (int rr = 0; rr < 16; ++rr) {
            const float pr = sm.part[w][rr];          // own-wave (lgkm dep auto)
            const int row = 16 * wr + rr;
            const bf16x4 x4 = *(const bf16x4*)(
                &sm.sA[(row * 512 + c0 * 2) ^ ((row & 7) << 4)]);
#pragma unroll
            for (int q = 0; q < 4; ++q) {
                const float x = (float)x4[q];
                s1a[q] += pr * x;
                if (wc == 0) s0a[q] += x;
            }
        }

        asm volatile("s_waitcnt lgkmcnt(0)" ::: "memory");  // part writes + sA reads done
        __builtin_amdgcn_s_barrier();                       // B1 (no vmcnt drain)
        __builtin_amdgcn_sched_barrier(0);

        // At rows complete: sum the 8 col-wave partials
        if (tid < TM) {
            const int g0 = (tid >> 4) * 8;
            float at = 0.f;
#pragma unroll
            for (int q = 0; q < 8; ++q) at += sm.part[g0 + q][tid & 15];
            At[tile * TM + tid] = at;
        }
        dswrite();                 // next tile (R loaded one full tile ago)
        gload(tile + 2 * NB_AT);   // stays in flight across B2
        asm volatile("s_waitcnt lgkmcnt(0)" ::: "memory");  // dswrite + part reads done
        __builtin_amdgcn_s_barrier();                       // B2
        __builtin_amdgcn_sched_barrier(0);
    }

    // ---- block reduce of ct partials (reuse sB region)
    __syncthreads();
    float* red1 = (float*)&sm.sB[0];       // [16][256]
    float* red2 = (float*)&sm.sB[16384];   // [2][256]
#pragma unroll
    for (int q = 0; q < 4; ++q) red1[w * 256 + c0 + q] = s1a[q];
    if (wc == 0)
#pragma unroll
        for (int q = 0; q < 4; ++q) red2[wr * 256 + c0 + q] = s0a[q];
    __syncthreads();
    if (tid < 256) {
        float a = 0.f;
#pragma unroll
        for (int g = 0; g < 16; ++g) a += red1[g * 256 + tid];
        atomicAdd(&s1g[tid], a);
    } else if (tid < 512) {
        const int c = tid - 256;
        atomicAdd(&s0g[c], red2[c] + red2[256 + c]);
    }
}

// ---------------------------------------------------------------- LSE stage 1
__global__ __launch_bounds__(256) void k_lse_part(const float* __restrict__ At,
                                                  float2* __restrict__ part) {
    const int tid = threadIdx.x;
    const int gid = blockIdx.x * 256 + tid;
    float m = -1e30f, s = 0.0f;
    for (int i = gid; i < T_N; i += 256 * 256) {
        const float x = At[i];
        if (x > m) { s = s * __expf(m - x) + 1.0f; m = x; }
        else s += __expf(x - m);
    }
    __shared__ float ms[256], ss[256];
    ms[tid] = m; ss[tid] = s;
    __syncthreads();
    for (int off = 128; off > 0; off >>= 1) {
        if (tid < off) {
            const float m2 = ms[tid + off], s2 = ss[tid + off];
            const float M = fmaxf(ms[tid], m2);
            ss[tid] = ss[tid] * __expf(ms[tid] - M) + s2 * __expf(m2 - M);
            ms[tid] = M;
        }
        __syncthreads();
    }
    if (tid == 0) part[blockIdx.x] = make_float2(ms[0], ss[0]);
}

// ---------------------------------------------------------------- final: LSE + ct
__global__ __launch_bounds__(256) void k_final(const float2* __restrict__ part2,
                                               const float* __restrict__ s1g,
                                               const float* __restrict__ s0g,
                                               float* __restrict__ lse,
                                               float* __restrict__ out) {
    const int tid = threadIdx.x;
    __shared__ float ms[256], ss[256];
    const float2 p = part2[tid];
    ms[tid] = p.x; ss[tid] = p.y;
    __syncthreads();
    for (int off = 128; off > 0; off >>= 1) {
        if (tid < off) {
            const float m2 = ms[tid + off], s2 = ss[tid + off];
            const float M = fmaxf(ms[tid], m2);
            ss[tid] = ss[tid] * __expf(ms[tid] - M) + s2 * __expf(m2 - M);
            ms[tid] = M;
        }
        __syncthreads();
    }
    __shared__ float Ls;
    if (tid == 0) { Ls = ms[0] + logf(ss[0]); *lse = Ls; }
    __syncthreads();
    out[T_N + tid] = s1g[tid] - Ls * s0g[tid];
}

// ---------------------------------------------------------------- alphat = At - LSE
__global__ __launch_bounds__(256) void k_alpha(const float* __restrict__ At,
                                               const float* __restrict__ lse,
                                               float* __restrict__ out) {
    const float L = *lse;
    const int i4 = blockIdx.x * 256 + threadIdx.x;
    if (i4 < T_N / 4) {
        float4 a = *(const float4*)(At + i4 * 4);
        a.x -= L; a.y -= L; a.z -= L; a.w -= L;
        *(float4*)(out + i4 * 4) = a;
    }
}

// ----------------------------------------------------------------
extern "C" void kernel_launch(void* const* d_in, const int* in_sizes, int n_in,
                              void* d_out, int out_size, void* d_ws, size_t ws_size,
                              hipStream_t stream) {
    const float* inputs = (const float*)d_in[0];  // (T, H)
    const float* hc     = (const float*)d_in[1];  // (1, H)
    const float* Wm     = (const float*)d_in[2];  // (H, H)
    const float* V      = (const float*)d_in[3];  // (H, 1)
    const float* W1     = (const float*)d_in[4];  // (H, H)
    float* out = (float*)d_out;                   // [alphat (T) | ct (H)]

    char* ws = (char*)d_ws;
    __bf16* WmT  = (__bf16*)ws;
    float* proj  = (float*)(ws + 131072);
    float* At    = (float*)(ws + 132096);
    float2* p2   = (float2*)(ws + 532096);
    float* s1g   = (float*)(ws + 536192);
    float* s0g   = (float*)(ws + 537216);
    float* lse   = (float*)(ws + 538240);

    k_prep<<<256, 256, 0, stream>>>(Wm, hc, W1, WmT, proj, s1g, s0g);
    k_at<<<NB_AT, 1024, 0, stream>>>(inputs, WmT, proj, V, At, s1g, s0g);
    k_lse_part<<<256, 256, 0, stream>>>(At, p2);
    k_final<<<1, 256, 0, stream>>>(p2, s1g, s0g, lse, out);
    k_alpha<<<98, 256, 0, stream>>>(At, lse, out);
}

// Round 8
// 75.443 us; speedup vs baseline: 2.2984x; 1.1637x over previous
//
#include <hip/hip_runtime.h>
#include <math.h>

#define T_N 100000
#define H_N 256
#define TM 32                  // tile rows
#define NT32 (T_N / TM)        // 3125 exact, no tail
#define NB_AT 512              // k_at grid: 2 blocks/CU

typedef __attribute__((ext_vector_type(8))) __bf16 bf16x8;
typedef __attribute__((ext_vector_type(4))) __bf16 bf16x4;
typedef __attribute__((ext_vector_type(4))) float f32x4;

// ws layout (bytes):
//       0 : WmT bf16 [256][256]   (131072)
//  131072 : proj f32 [256]        (1024)
//  132096 : At   f32 [100000]     (400000)
//  532096 : part2 float2[256]     (2048)
//  536192 : s1g  f32[256]         (1024)
//  537216 : s0g  f32[256]         (1024)
//  538240 : lse  f32              (4)

__device__ __forceinline__ float tanh_fast(float x) {
    float e = __expf(2.0f * x);
    return 1.0f - 2.0f / (e + 1.0f);
}

// ---------------------------------------------------------------- prep
__global__ __launch_bounds__(256) void k_prep(const float* __restrict__ Wm,
                                              const float* __restrict__ hc,
                                              const float* __restrict__ W1,
                                              __bf16* __restrict__ WmT,
                                              float* __restrict__ proj,
                                              float* __restrict__ s1g,
                                              float* __restrict__ s0g) {
    const int j = blockIdx.x;
    const int t = threadIdx.x;
    WmT[j * H_N + t] = (__bf16)Wm[t * H_N + j];   // B^T, k-contiguous
    __shared__ float red[H_N];
    red[t] = hc[t] * W1[j * H_N + t];
    __syncthreads();
    for (int off = 128; off > 0; off >>= 1) {
        if (t < off) red[t] += red[t + off];
        __syncthreads();
    }
    if (t == 0) proj[j] = red[0];
    if (j == 0) { s1g[t] = 0.0f; s0g[t] = 0.0f; }
}

// ---------------------------------------------------------------- fused At + ct partials
// 1024 thr = 16 waves. Wave (wr=w>>3, wc=w&7): rows 16wr..+16 (M1),
// cols 32wc..+32 (N2). B-fragments in REGISTERS (breg[8][2] = 64 VGPR),
// filled once from L2-hot WmT — no sB in LDS. LDS = 2x16KB sA + part = 33KB
// -> 2 blocks/CU (8 waves/SIMD). 2 raw barriers/tile, gloads stay in flight.
__global__ __launch_bounds__(1024, 4) void k_at(const float* __restrict__ Mt,
                                                const __bf16* __restrict__ WmT,
                                                const float* __restrict__ proj,
                                                const float* __restrict__ V,
                                                float* __restrict__ At,
                                                float* __restrict__ s1g,
                                                float* __restrict__ s0g) {
    const int tid = threadIdx.x;
    const int lane = tid & 63;
    const int w = tid >> 6;     // 0..15
    const int wr = w >> 3;      // 0..1
    const int wc = w & 7;       // 0..7
    const int l15 = lane & 15;
    const int lg = lane >> 4;   // 0..3

    struct SMem {
        __align__(16) char sA[2][TM * 512];  // [32][256] bf16, XOR-swizzled
        float part[16][16];                  // [wave][row-in-16-group]
    };
    __shared__ SMem sm;

    // ---- B fragments resident in registers (fill once; WmT L2-hot)
    bf16x8 breg[8][2];
#pragma unroll
    for (int ks = 0; ks < 8; ++ks)
#pragma unroll
        for (int fc = 0; fc < 2; ++fc)
            breg[ks][fc] = *(const bf16x8*)(
                WmT + (32 * wc + 16 * fc + l15) * H_N + 32 * ks + 8 * lg);
    float pj[2], vj[2];
#pragma unroll
    for (int fc = 0; fc < 2; ++fc) {
        const int n = 32 * wc + 16 * fc + l15;
        pj[fc] = proj[n];
        vj[fc] = V[n];
    }

    // staging: 2048 float4 slots; f = i*1024+tid -> row=f>>6, c4=f&63
    float4 R[2];
    auto gload = [&](int tile) {
        const int tt = (tile < NT32) ? tile : (NT32 - 1);
#pragma unroll
        for (int i = 0; i < 2; ++i) {
            const int f = i * 1024 + tid;
            R[i] = *(const float4*)(Mt + (size_t)(tt * TM + (f >> 6)) * H_N + (f & 63) * 4);
        }
    };
    auto dswrite = [&](int buf) {
#pragma unroll
        for (int i = 0; i < 2; ++i) {
            const int f = i * 1024 + tid;
            const int row = f >> 6, c4 = f & 63;
            bf16x4 b;
            b[0] = (__bf16)R[i].x; b[1] = (__bf16)R[i].y;
            b[2] = (__bf16)R[i].z; b[3] = (__bf16)R[i].w;
            *(bf16x4*)(&sm.sA[buf][(row * 512 + c4 * 8) ^ ((row & 7) << 4)]) = b;
        }
    };

    float s1a[4] = {0.f, 0.f, 0.f, 0.f};
    float s0a[4] = {0.f, 0.f, 0.f, 0.f};
    const int r1 = tid & 15;        // ct row pair (r1, r1+16)
    const int c4 = tid >> 4 & 63;   // ct cols 4c4..+4

    int tile = blockIdx.x;
    gload(tile);
    dswrite(0);
    __syncthreads();            // one-time full barrier (sA[0] visible)
    gload(tile + NB_AT);        // in flight across the whole first tile

    int cur = 0;
    for (; tile < NT32; tile += NB_AT) {
        // ---- MFMA phase: A from sA[cur], B from registers
        f32x4 acc[2];
#pragma unroll
        for (int fc = 0; fc < 2; ++fc) {
            f32x4 z = {0.f, 0.f, 0.f, 0.f};
            acc[fc] = z;
        }
        const int rbase = (16 * wr + l15) * 512;
        const int rswz = ((16 * wr + l15) & 7) << 4;
#pragma unroll
        for (int ks = 0; ks < 8; ++ks) {
            const bf16x8 af = *(const bf16x8*)(
                &sm.sA[cur][rbase + ((64 * ks + 16 * lg) ^ rswz)]);
            acc[0] = __builtin_amdgcn_mfma_f32_16x16x32_bf16(af, breg[ks][0], acc[0], 0, 0, 0);
            acc[1] = __builtin_amdgcn_mfma_f32_16x16x32_bf16(af, breg[ks][1], acc[1], 0, 0, 0);
        }

        // ---- epilogue: col-partial row sums over this wave's 32 cols
#pragma unroll
        for (int i = 0; i < 4; ++i) {
            float p = tanh_fast(acc[0][i] + pj[0]) * vj[0]
                    + tanh_fast(acc[1][i] + pj[1]) * vj[1];
            p += __shfl_xor(p, 1);
            p += __shfl_xor(p, 2);
            p += __shfl_xor(p, 4);
            p += __shfl_xor(p, 8);
            if (l15 == 0) sm.part[w][4 * lg + i] = p;
        }

        asm volatile("s_waitcnt lgkmcnt(0)" ::: "memory");  // part + sA[cur] MFMA reads done
        __builtin_amdgcn_s_barrier();                       // B1 (no vmcnt drain)
        __builtin_amdgcn_sched_barrier(0);

        // ---- assemble At rows for this thread's 2 rows; ct partials; stage next
        float at1 = 0.f, at2 = 0.f;
#pragma unroll
        for (int q = 0; q < 8; ++q) {
            at1 += sm.part[q][r1];
            at2 += sm.part[8 + q][r1];
        }
        if (tid < TM) At[tile * TM + tid] = (tid < 16) ? at1 : at2;

        const int swz = (r1 & 7) << 4;  // (r1+16)&7 == r1&7
        const bf16x4 x1 = *(const bf16x4*)(&sm.sA[cur][(r1 * 512 + c4 * 8) ^ swz]);
        const bf16x4 x2 = *(const bf16x4*)(&sm.sA[cur][((r1 + 16) * 512 + c4 * 8) ^ swz]);
#pragma unroll
        for (int q = 0; q < 4; ++q) {
            const float a = (float)x1[q], b = (float)x2[q];
            s1a[q] += at1 * a + at2 * b;
            s0a[q] += a + b;
        }

        dswrite(cur ^ 1);          // next tile (R loaded one full tile ago)
        gload(tile + 2 * NB_AT);   // stays in flight across B2

        asm volatile("s_waitcnt lgkmcnt(0)" ::: "memory");  // dswrite + part/sA reads done
        __builtin_amdgcn_s_barrier();                       // B2
        __builtin_amdgcn_sched_barrier(0);
        cur ^= 1;
    }

    // ---- block reduce of ct partials (reuse sA), then global atomics
    __syncthreads();
    float* red1 = (float*)&sm.sA[0][0];  // [16][256]
    float* red2 = (float*)&sm.sA[1][0];  // [16][256]
#pragma unroll
    for (int q = 0; q < 4; ++q) {
        red1[r1 * 256 + 4 * c4 + q] = s1a[q];
        red2[r1 * 256 + 4 * c4 + q] = s0a[q];
    }
    __syncthreads();
    if (tid < 256) {
        float a = 0.f;
#pragma unroll
        for (int g = 0; g < 16; ++g) a += red1[g * 256 + tid];
        atomicAdd(&s1g[tid], a);
    } else if (tid < 512) {
        const int c = tid - 256;
        float a = 0.f;
#pragma unroll
        for (int g = 0; g < 16; ++g) a += red2[g * 256 + c];
        atomicAdd(&s0g[c], a);
    }
}

// ---------------------------------------------------------------- LSE stage 1
__global__ __launch_bounds__(256) void k_lse_part(const float* __restrict__ At,
                                                  float2* __restrict__ part) {
    const int tid = threadIdx.x;
    const int gid = blockIdx.x * 256 + tid;
    float m = -1e30f, s = 0.0f;
    for (int i = gid; i < T_N; i += 256 * 256) {
        const float x = At[i];
        if (x > m) { s = s * __expf(m - x) + 1.0f; m = x; }
        else s += __expf(x - m);
    }
    __shared__ float ms[256], ss[256];
    ms[tid] = m; ss[tid] = s;
    __syncthreads();
    for (int off = 128; off > 0; off >>= 1) {
        if (tid < off) {
            const float m2 = ms[tid + off], s2 = ss[tid + off];
            const float M = fmaxf(ms[tid], m2);
            ss[tid] = ss[tid] * __expf(ms[tid] - M) + s2 * __expf(m2 - M);
            ms[tid] = M;
        }
        __syncthreads();
    }
    if (tid == 0) part[blockIdx.x] = make_float2(ms[0], ss[0]);
}

// ---------------------------------------------------------------- final: LSE + ct
__global__ __launch_bounds__(256) void k_final(const float2* __restrict__ part2,
                                               const float* __restrict__ s1g,
                                               const float* __restrict__ s0g,
                                               float* __restrict__ lse,
                                               float* __restrict__ out) {
    const int tid = threadIdx.x;
    __shared__ float ms[256], ss[256];
    const float2 p = part2[tid];
    ms[tid] = p.x; ss[tid] = p.y;
    __syncthreads();
    for (int off = 128; off > 0; off >>= 1) {
        if (tid < off) {
            const float m2 = ms[tid + off], s2 = ss[tid + off];
            const float M = fmaxf(ms[tid], m2);
            ss[tid] = ss[tid] * __expf(ms[tid] - M) + s2 * __expf(m2 - M);
            ms[tid] = M;
        }
        __syncthreads();
    }
    __shared__ float Ls;
    if (tid == 0) { Ls = ms[0] + logf(ss[0]); *lse = Ls; }
    __syncthreads();
    out[T_N + tid] = s1g[tid] - Ls * s0g[tid];
}

// ---------------------------------------------------------------- alphat = At - LSE
__global__ __launch_bounds__(256) void k_alpha(const float* __restrict__ At,
                                               const float* __restrict__ lse,
                                               float* __restrict__ out) {
    const float L = *lse;
    const int i4 = blockIdx.x * 256 + threadIdx.x;
    if (i4 < T_N / 4) {
        float4 a = *(const float4*)(At + i4 * 4);
        a.x -= L; a.y -= L; a.z -= L; a.w -= L;
        *(float4*)(out + i4 * 4) = a;
    }
}

// ----------------------------------------------------------------
extern "C" void kernel_launch(void* const* d_in, const int* in_sizes, int n_in,
                              void* d_out, int out_size, void* d_ws, size_t ws_size,
                              hipStream_t stream) {
    const float* inputs = (const float*)d_in[0];  // (T, H)
    const float* hc     = (const float*)d_in[1];  // (1, H)
    const float* Wm     = (const float*)d_in[2];  // (H, H)
    const float* V      = (const float*)d_in[3];  // (H, 1)
    const float* W1     = (const float*)d_in[4];  // (H, H)
    float* out = (float*)d_out;                   // [alphat (T) | ct (H)]

    char* ws = (char*)d_ws;
    __bf16* WmT  = (__bf16*)ws;
    float* proj  = (float*)(ws + 131072);
    float* At    = (float*)(ws + 132096);
    float2* p2   = (float2*)(ws + 532096);
    float* s1g   = (float*)(ws + 536192);
    float* s0g   = (float*)(ws + 537216);
    float* lse   = (float*)(ws + 538240);

    k_prep<<<256, 256, 0, stream>>>(Wm, hc, W1, WmT, proj, s1g, s0g);
    k_at<<<NB_AT, 1024, 0, stream>>>(inputs, WmT, proj, V, At, s1g, s0g);
    k_lse_part<<<256, 256, 0, stream>>>(At, p2);
    k_final<<<1, 256, 0, stream>>>(p2, s1g, s0g, lse, out);
    k_alpha<<<98, 256, 0, stream>>>(At, lse, out);
}